// Round 1
// baseline (47.158 us; speedup 1.0000x reference)
//
#include <hip/hip_runtime.h>
#include <hip/hip_bf16.h>

// Problem constants (from reference)
#define VOCAB   128000
#define DIM     2048
#define N_TRAIN 256
#define N_TOKENS (4 * 4096)   // BATCH * SEQ

// One block per output token row. 256 threads.
// out[row, :] = W[t, :] + sum over k with token_indices[k]==t of delta_rows[k, :]
// delta layout (COO column-major): delta_rows[k][c] = delta[c * N_TRAIN + k]
__global__ __launch_bounds__(256) void gather_adapted_rows(
    const int* __restrict__ x,          // [N_TOKENS] token ids
    const float* __restrict__ W,        // [VOCAB, DIM]
    const float* __restrict__ delta,    // [DIM * N_TRAIN], col-major over (k, c)
    const int* __restrict__ tok_idx,    // [N_TRAIN]
    float* __restrict__ out)            // [N_TOKENS, DIM]
{
    __shared__ int s_match_k[N_TRAIN];
    __shared__ int s_nmatch;

    const int row = blockIdx.x;
    const int tid = threadIdx.x;
    const int t = x[row];   // broadcast scalar load

    if (tid == 0) s_nmatch = 0;
    __syncthreads();

    // 256 threads each check one trained-token slot
    if (tok_idx[tid] == t) {
        int slot = atomicAdd(&s_nmatch, 1);
        s_match_k[slot] = tid;
    }
    __syncthreads();

    const int nm = s_nmatch;
    const float* __restrict__ wrow = W + (size_t)t * DIM;
    float* __restrict__ orow = out + (size_t)row * DIM;

    // 2048 floats / 256 threads = 8 floats = 2 float4 per thread.
    // float4 index p*256 + tid -> consecutive lanes hit consecutive 16B: coalesced.
    #pragma unroll
    for (int p = 0; p < 2; ++p) {
        const int f4 = p * 256 + tid;   // 0..511
        float4 v = reinterpret_cast<const float4*>(wrow)[f4];
        // Rare path: accumulate delta rows for matched trained tokens
        for (int m = 0; m < nm; ++m) {
            const int k = s_match_k[m];
            const int c = f4 * 4;
            v.x += delta[(size_t)(c + 0) * N_TRAIN + k];
            v.y += delta[(size_t)(c + 1) * N_TRAIN + k];
            v.z += delta[(size_t)(c + 2) * N_TRAIN + k];
            v.w += delta[(size_t)(c + 3) * N_TRAIN + k];
        }
        reinterpret_cast<float4*>(orow)[f4] = v;
    }
}

extern "C" void kernel_launch(void* const* d_in, const int* in_sizes, int n_in,
                              void* d_out, int out_size, void* d_ws, size_t ws_size,
                              hipStream_t stream) {
    const int*   x       = (const int*)  d_in[0];  // [16384]
    const float* W       = (const float*)d_in[1];  // [128000*2048]
    const float* delta   = (const float*)d_in[2];  // [2048*256]
    const int*   tok_idx = (const int*)  d_in[3];  // [256]
    float* out = (float*)d_out;

    dim3 grid(N_TOKENS);
    dim3 block(256);
    gather_adapted_rows<<<grid, block, 0, stream>>>(x, W, delta, tok_idx, out);
}